// Round 1
// baseline (735.364 us; speedup 1.0000x reference)
//
#include <hip/hip_runtime.h>
#include <cstdint>
#include <cstddef>

#define H2 1024
#define TT 512
#define NSTEPS 64

using floatx4 = __attribute__((__ext_vector_type__(4))) float;
using half8   = __attribute__((__ext_vector_type__(8))) _Float16;
using half4   = __attribute__((__ext_vector_type__(4))) _Float16;

__device__ __forceinline__ float tanh_fast(float x) {
  // 1 - 2/(e^{2x}+1); saturates correctly for |x| large (inf -> 1, 0 -> -1)
  return 1.0f - 2.0f / (__expf(2.0f * x) + 1.0f);
}

// ---------------------------------------------------------------------------
// Recurrence step: v = W @ u_prev_normalized + b ; norm2 += v^2 (atomic)
// grid 256 blocks x 64 threads (1 wave). Block b handles rows 4b..4b+3.
// ---------------------------------------------------------------------------
__global__ __launch_bounds__(64) void step_kernel(
    const float* __restrict__ W, const float* __restrict__ bias,
    const float* __restrict__ u0, float* __restrict__ vbuf,
    float* __restrict__ norm2, int step) {
  int l = threadIdx.x;          // 0..63
  int b = blockIdx.x;           // 0..255
  int sub = l >> 4, seg = l & 15;
  int r = b * 4 + sub;

  const float* up = (step == 0) ? u0 : (vbuf + (size_t)(step - 1) * H2);
  float rs = 1.0f;
  if (step > 0) rs = 1.0f / fmaxf(sqrtf(norm2[step - 1]), 1e-12f);

  const float4* wr = reinterpret_cast<const float4*>(W + (size_t)r * H2);
  const float4* ur = reinterpret_cast<const float4*>(up);

  float acc = 0.f;
#pragma unroll
  for (int j = 0; j < 16; ++j) {
    int idx = j * 16 + seg;     // float4 index 0..255
    float4 w4 = wr[idx];
    float4 u4 = ur[idx];
    acc += w4.x * u4.x + w4.y * u4.y + w4.z * u4.z + w4.w * u4.w;
  }
  // reduce over seg (low 4 lane bits)
#pragma unroll
  for (int off = 1; off <= 8; off <<= 1) acc += __shfl_xor(acc, off, 64);

  float v = 0.f;
  if (seg == 0) {
    v = acc * rs + bias[r];     // dot(W_row, u*rs) = rs*dot(W_row,u)
    vbuf[(size_t)step * H2 + r] = v;
  }
  float nv = (seg == 0) ? v * v : 0.f;
  nv += __shfl_xor(nv, 16, 64);
  nv += __shfl_xor(nv, 32, 64);
  if (l == 0) atomicAdd(&norm2[step], nv);
}

// ---------------------------------------------------------------------------
// Fused GEMM + tanh + score partial reduction.
// Y[e,t] = sum_d W[e,d] * h[n,d,t]  (fp16 MFMA, fp32 accum)
// scores[n,t] += sum_e tanh(Y+b[e]) * u_ws[n,e]
// grid (8 e-tiles, 4 t-tiles, 64 n), block 256 = 4 waves, tile 128x128, BK=32
// ---------------------------------------------------------------------------
__global__ __launch_bounds__(256) void gemm_scores(
    const float* __restrict__ h, const float* __restrict__ W,
    const float* __restrict__ bias, const float* __restrict__ vbuf,
    const float* __restrict__ norm2, float* __restrict__ scores) {
  int e_base = blockIdx.x * 128;
  int t_base = blockIdx.y * 128;
  int n = blockIdx.z;
  int tid = threadIdx.x;
  int lane = tid & 63, w = tid >> 6;
  int q = lane >> 4, m = lane & 15;
  int eoff = (w & 1) * 64, toff = (w >> 1) * 64;

  __shared__ __align__(16) _Float16 Ash[128][40];  // [e][k], pad->40
  __shared__ __align__(16) _Float16 Bsh[128][40];  // [t][k] (transposed), pad->40

  floatx4 zero = {0.f, 0.f, 0.f, 0.f};
  floatx4 acc[4][4];
#pragma unroll
  for (int i = 0; i < 4; ++i)
#pragma unroll
    for (int j = 0; j < 4; ++j) acc[i][j] = zero;

  const float* hb = h + (size_t)n * H2 * TT + t_base;

  int r0 = tid >> 3, c4 = (tid & 7) << 2;     // A staging: row, col4
  int kk4 = (tid >> 5) << 2, tl = tid & 31;   // B staging: k-group, t-lane

  for (int k0 = 0; k0 < H2; k0 += 32) {
    // ---- stage A: W[e_base..+128)[k0..+32) -> fp16 Ash[e][k]
#pragma unroll
    for (int p = 0; p < 4; ++p) {
      int r = p * 32 + r0;
      const float* wp = W + (size_t)(e_base + r) * H2 + k0 + c4;
      float4 wv = *reinterpret_cast<const float4*>(wp);
      half4 hv = {(_Float16)wv.x, (_Float16)wv.y, (_Float16)wv.z, (_Float16)wv.w};
      *reinterpret_cast<half4*>(&Ash[r][c4]) = hv;
    }
    // ---- stage B: h[n][k0..+32)[t_base..+128) -> fp16 Bsh[t][k] (transposed)
    const float* hp = hb + (size_t)(k0 + kk4) * TT;
#pragma unroll
    for (int jj = 0; jj < 4; ++jj) {
      int t = tl + 32 * jj;
      float x0 = hp[t];
      float x1 = hp[TT + t];
      float x2 = hp[2 * TT + t];
      float x3 = hp[3 * TT + t];
      half4 hv = {(_Float16)x0, (_Float16)x1, (_Float16)x2, (_Float16)x3};
      *reinterpret_cast<half4*>(&Bsh[t][kk4]) = hv;
    }
    __syncthreads();

    half8 af[4], bf[4];
#pragma unroll
    for (int i = 0; i < 4; ++i)
      af[i] = *reinterpret_cast<const half8*>(&Ash[eoff + i * 16 + m][q * 8]);
#pragma unroll
    for (int j = 0; j < 4; ++j)
      bf[j] = *reinterpret_cast<const half8*>(&Bsh[toff + j * 16 + m][q * 8]);
#pragma unroll
    for (int i = 0; i < 4; ++i)
#pragma unroll
      for (int j = 0; j < 4; ++j)
        acc[i][j] = __builtin_amdgcn_mfma_f32_16x16x32_f16(af[i], bf[j], acc[i][j], 0, 0, 0);
    __syncthreads();
  }

  // ---- epilogue: tanh + multiply by u_ws, reduce over e within block
  float* uloc = reinterpret_cast<float*>(&Ash[0][0]);  // reuse LDS
  float* bloc = uloc + 128;
  if (tid < 128) {
    float rs = 1.0f / fmaxf(sqrtf(norm2[n]), 1e-12f);
    uloc[tid] = vbuf[(size_t)n * H2 + e_base + tid] * rs;
    bloc[tid] = bias[e_base + tid];
  }
  __syncthreads();

  float part[4] = {0.f, 0.f, 0.f, 0.f};
#pragma unroll
  for (int i = 0; i < 4; ++i) {
#pragma unroll
    for (int reg = 0; reg < 4; ++reg) {
      int el = eoff + i * 16 + q * 4 + reg;   // C layout: row = quad*4 + reg
      float ub = uloc[el];
      float bb = bloc[el];
#pragma unroll
      for (int j = 0; j < 4; ++j) {
        float y = acc[i][j][reg] + bb;
        part[j] += tanh_fast(y) * ub;
      }
    }
  }
#pragma unroll
  for (int j = 0; j < 4; ++j) {
    part[j] += __shfl_xor(part[j], 16, 64);   // reduce over quads
    part[j] += __shfl_xor(part[j], 32, 64);
    if (lane < 16) {
      int t = t_base + toff + j * 16 + lane;  // C layout: col = lane&15
      atomicAdd(&scores[(size_t)n * TT + t], part[j]);
    }
  }
}

// ---------------------------------------------------------------------------
// Fused softmax(scores row) + weighted sum s[n,d] = sum_t h[n,d,t]*a[n,t]
// grid (16 d-slices, 64 n), block 256 = 4 waves; each block: 64 d rows.
// ---------------------------------------------------------------------------
__global__ __launch_bounds__(256) void out_kernel(
    const float* __restrict__ h, const float* __restrict__ scores,
    float* __restrict__ out) {
  int n = blockIdx.y;
  int ds = blockIdx.x;
  int tid = threadIdx.x;
  int w = tid >> 6, lane = tid & 63;

  __shared__ float sa[TT];
  __shared__ float wred[8];

  float s0 = scores[(size_t)n * TT + tid];
  float s1 = scores[(size_t)n * TT + 256 + tid];

  // block max
  float mx = fmaxf(s0, s1);
#pragma unroll
  for (int off = 32; off >= 1; off >>= 1) mx = fmaxf(mx, __shfl_xor(mx, off, 64));
  if (lane == 0) wred[w] = mx;
  __syncthreads();
  mx = fmaxf(fmaxf(wred[0], wred[1]), fmaxf(wred[2], wred[3]));

  float e0 = __expf(s0 - mx);
  float e1 = __expf(s1 - mx);
  float ssum = e0 + e1;
#pragma unroll
  for (int off = 32; off >= 1; off >>= 1) ssum += __shfl_xor(ssum, off, 64);
  if (lane == 0) wred[4 + w] = ssum;
  __syncthreads();
  ssum = wred[4] + wred[5] + wred[6] + wred[7];
  float inv = 1.0f / ssum;
  sa[tid] = e0 * inv;
  sa[tid + 256] = e1 * inv;
  __syncthreads();

  // weighted sum: wave w handles rows d0 + w*16 .. +15
  int d0 = ds * 64 + w * 16;
  const float4* hb = reinterpret_cast<const float4*>(h + (size_t)n * H2 * TT);
#pragma unroll 1
  for (int rr = 0; rr < 16; ++rr) {
    int d = d0 + rr;
    const float4* hr = hb + (size_t)d * (TT / 4);
    float4 a4 = hr[lane];
    float4 b4 = hr[64 + lane];
    int t0 = 4 * lane;
    float acc = a4.x * sa[t0] + a4.y * sa[t0 + 1] + a4.z * sa[t0 + 2] + a4.w * sa[t0 + 3]
              + b4.x * sa[256 + t0] + b4.y * sa[256 + t0 + 1]
              + b4.z * sa[256 + t0 + 2] + b4.w * sa[256 + t0 + 3];
#pragma unroll
    for (int off = 1; off <= 32; off <<= 1) acc += __shfl_xor(acc, off, 64);
    if (lane == 0) out[(size_t)n * H2 + d] = acc;
  }
}

// ---------------------------------------------------------------------------
extern "C" void kernel_launch(void* const* d_in, const int* in_sizes, int n_in,
                              void* d_out, int out_size, void* d_ws, size_t ws_size,
                              hipStream_t stream) {
  const float* h    = (const float*)d_in[0];  // (64, 1024, 512)
  const float* W    = (const float*)d_in[1];  // (1024, 1024)
  const float* bias = (const float*)d_in[2];  // (1024,)
  const float* u0   = (const float*)d_in[3];  // (1024,)
  float* out = (float*)d_out;                 // (64, 1024)

  float* wsf    = (float*)d_ws;
  float* norm2  = wsf;                        // 64
  float* scores = wsf + 64;                   // 64*512
  float* vbuf   = wsf + 64 + NSTEPS * TT;     // 64*1024

  // zero norm2 + scores (atomically accumulated)
  hipMemsetAsync(d_ws, 0, (size_t)(64 + NSTEPS * TT) * sizeof(float), stream);

  // sequential recurrence: 64 launches
  for (int i = 0; i < NSTEPS; ++i) {
    step_kernel<<<dim3(256), dim3(64), 0, stream>>>(W, bias, u0, vbuf, norm2, i);
  }

  // fused GEMM + tanh + score reduction
  gemm_scores<<<dim3(8, 4, 64), dim3(256), 0, stream>>>(h, W, bias, vbuf, norm2, scores);

  // fused softmax + weighted sum
  out_kernel<<<dim3(16, 64), dim3(256), 0, stream>>>(h, scores, out);

  (void)in_sizes; (void)n_in; (void)out_size; (void)ws_size;
}